// Round 3
// baseline (568.212 us; speedup 1.0000x reference)
//
#include <hip/hip_runtime.h>

#define HW 3136
#define NB 8
#define CD 128
// C^-0.5 * log2(e), folded into the Q projection so attn uses exp2 directly
#define QSCALE 0.12751750206f

typedef __attribute__((ext_vector_type(8))) short short8;
typedef __attribute__((ext_vector_type(4))) float floatx4;
typedef __attribute__((ext_vector_type(16))) float floatx16;
typedef __attribute__((ext_vector_type(4))) unsigned short ushort4v;

static __device__ __forceinline__ unsigned short f2b(float f){
  union { float f; unsigned u; } v; v.f = f;
  unsigned r = v.u + 0x7FFFu + ((v.u >> 16) & 1u);
  return (unsigned short)(r >> 16);
}
static __device__ __forceinline__ unsigned short f2b_trunc(float f){
  union { float f; unsigned u; } v; v.f = f;
  return (unsigned short)(v.u >> 16);
}
static __device__ __forceinline__ float b2f(unsigned short h){
  union { unsigned u; float f; } v; v.u = ((unsigned)h) << 16;
  return v.f;
}

// ---------------------------------------------------------------------------
// 1x1 conv projections via MFMA; W staged once, all 8 batches looped with
// double-buffered X^T. grid (49 hw-tiles, 5 jobs).
// ---------------------------------------------------------------------------
__global__ __launch_bounds__(256,2) void proj_kernel(
    const float* __restrict__ s, const float* __restrict__ t1, const float* __restrict__ t2,
    const float* __restrict__ wq, const float* __restrict__ bq,
    const float* __restrict__ wk, const float* __restrict__ bk,
    const float* __restrict__ wv, const float* __restrict__ bv,
    unsigned short* __restrict__ qkv)
{
  __shared__ __align__(16) unsigned short WL[CD][136];      // 34.8 KB
  __shared__ __align__(16) unsigned short XT[2][64][136];   // 34.8 KB
  const int job = blockIdx.y;
  const float* x; const float* w; const float* bias; float scl; int cmajor; size_t dstoff;
  switch(job){
    case 0: x=s;  w=wq; bias=bq; scl=QSCALE; cmajor=0; dstoff=0; break;
    case 1: x=t1; w=wk; bias=bk; scl=1.f;    cmajor=0; dstoff=1; break;
    case 2: x=t1; w=wv; bias=bv; scl=1.f;    cmajor=1; dstoff=2; break;
    case 3: x=t2; w=wk; bias=bk; scl=1.f;    cmajor=0; dstoff=3; break;
    default:x=t2; w=wv; bias=bv; scl=1.f;    cmajor=1; dstoff=4; break;
  }
  const size_t TS = (size_t)NB*HW*CD;
  const int hw0 = blockIdx.x * 64;
  const int tid = threadIdx.x;

  for (int i = 0; i < 16; i++){
    int flat = tid + i*256;
    int o = flat >> 5, cq = (flat & 31)*4;
    floatx4 wv4 = *(const floatx4*)(w + (size_t)o*CD + cq);
    ushort4v pk;
    for (int j=0;j<4;j++) pk[j] = f2b(wv4[j]);
    *(ushort4v*)&WL[o][cq] = pk;
  }

  const int m = tid & 15, quad = (tid >> 4) & 3, wv_ = tid >> 6;
  float bb[8];
  for (int nt=0;nt<8;nt++) bb[nt] = bias[nt*16 + m];

  // prologue stage for b=0
  {
    const float* xb = x + hw0;
    for (int i = 0; i < 8; i++){
      int flat = (tid + i*256)*4;
      int c = flat >> 6, hh = flat & 63;
      floatx4 xv = *(const floatx4*)(xb + (size_t)c*HW + hh);
      for (int j=0;j<4;j++) XT[0][hh+j][c] = f2b(xv[j]);
    }
  }

  for (int b = 0; b < NB; b++){
    __syncthreads();
    if (b+1 < NB){
      const float* xb = x + (size_t)(b+1)*CD*HW + hw0;
      int buf = (b+1)&1;
      for (int i = 0; i < 8; i++){
        int flat = (tid + i*256)*4;
        int c = flat >> 6, hh = flat & 63;
        floatx4 xv = *(const floatx4*)(xb + (size_t)c*HW + hh);
        for (int j=0;j<4;j++) XT[buf][hh+j][c] = f2b(xv[j]);
      }
    }
    const int cur = b & 1;
    short8 af[4];
    for (int dk=0;dk<4;dk++)
      af[dk] = *(const short8*)&XT[cur][wv_*16 + m][dk*32 + quad*8];

    unsigned short* dstK = qkv + dstoff*TS + ((size_t)b*HW + hw0)*CD;
    unsigned short* dstV = qkv + dstoff*TS + (size_t)b*CD*HW;
    for (int nt=0;nt<8;nt++){
      floatx4 acc = {bb[nt],bb[nt],bb[nt],bb[nt]};
      for (int dk=0;dk<4;dk++){
        short8 bf = *(const short8*)&WL[nt*16 + m][dk*32 + quad*8];
        acc = __builtin_amdgcn_mfma_f32_16x16x32_bf16(af[dk], bf, acc, 0,0,0);
      }
      if (!cmajor){
        for (int r=0;r<4;r++)
          dstK[(size_t)(wv_*16 + quad*4 + r)*CD + nt*16 + m] = f2b(acc[r]*scl);
      } else {
        ushort4v pk;
        for (int r=0;r<4;r++) pk[r] = f2b(acc[r]*scl);
        *(ushort4v*)&dstV[(size_t)(nt*16 + m)*HW + hw0 + wv_*16 + quad*4] = pk;
      }
    }
  }
}

// ---------------------------------------------------------------------------
// Flash attention, 32-row waves, 32x32x16 MFMA, q-tile 128, shfl-based P
// transpose (no P LDS round-trip). grid (25, 8, 2).
// ---------------------------------------------------------------------------
#define KSTR 132
#define VSTR 68
#define KL_E (64*KSTR)
#define VL_E (128*VSTR)

__global__ __launch_bounds__(256,2) void attn_kernel(
    const unsigned short* __restrict__ qkv,
    unsigned short* __restrict__ Og)
{
  __shared__ __align__(16) unsigned short smem[KL_E + VL_E];  // 34304 B
  __shared__ float invL[4][32];
  unsigned short (*Kl)[KSTR] = (unsigned short(*)[KSTR])smem;
  unsigned short (*Vl)[VSTR] = (unsigned short(*)[VSTR])(smem + KL_E);

  const int qt = blockIdx.x;
  const int b  = blockIdx.y;
  const int t  = blockIdx.z;
  const size_t TS = (size_t)NB*HW*CD;
  const unsigned short* Q = qkv + (size_t)b*HW*CD;
  const unsigned short* K = qkv + TS*(size_t)(1 + 2*t) + (size_t)b*HW*CD;
  const unsigned short* V = qkv + TS*(size_t)(2 + 2*t) + (size_t)b*CD*HW;

  const int tid  = threadIdx.x;
  const int w    = tid >> 6;
  const int lane = tid & 63;
  const int ln   = lane & 31;
  const int h    = lane >> 5;
  const int q0w  = qt*128 + w*32;

  // Q fragments (B-operand: rows = q on lane&31, k chunks of 16 channels)
  short8 qf[8];
  {
    int qrow = q0w + ln; if (qrow >= HW) qrow = HW-1;
    const unsigned short* qr = Q + (size_t)qrow*CD + h*8;
    for (int dk=0;dk<8;dk++) qf[dk] = *(const short8*)(qr + dk*16);
  }
  floatx16 Oc[4];
  for (int i=0;i<4;i++) Oc[i] = (floatx16)0.f;
  float lr = 0.f;

  const unsigned short* kg = K + (size_t)(tid>>4)*CD + (tid&15)*8;
  const unsigned short* vg = V + (size_t)(tid>>3)*HW + (tid&7)*8;
  unsigned short* klds = &Kl[tid>>4][(tid&15)*8];
  unsigned short* vlds = &Vl[tid>>3][(tid&7)*8];

  short8 kpre[4], vpre[4];
  for (int i=0;i<4;i++) kpre[i] = *(const short8*)(kg + (size_t)i*16*CD);
  for (int i=0;i<4;i++) vpre[i] = *(const short8*)(vg + (size_t)i*32*HW);

  for (int kt = 0; kt < HW/64; kt++){
    __syncthreads();
    for (int i=0;i<4;i++) *(short8*)(klds + i*16*KSTR) = kpre[i];
    for (int i=0;i<4;i++) *(short8*)(vlds + i*32*VSTR) = vpre[i];
    __syncthreads();
    if (kt < HW/64 - 1){
      kg += 64*CD; vg += 64;
      for (int i=0;i<4;i++) kpre[i] = *(const short8*)(kg + (size_t)i*16*CD);
      for (int i=0;i<4;i++) vpre[i] = *(const short8*)(vg + (size_t)i*32*HW);
    }

    // S^T = K . Q^T : A = K rows (32 keys), B = Q rows; D[k][q], q on lanes
    floatx16 s0 = (floatx16)0.f, s1 = (floatx16)0.f;
    for (int dk=0;dk<8;dk++){
      short8 kf = *(const short8*)&Kl[ln][dk*16 + h*8];
      s0 = __builtin_amdgcn_mfma_f32_32x32x16_bf16(kf, qf[dk], s0, 0,0,0);
    }
    for (int dk=0;dk<8;dk++){
      short8 kf = *(const short8*)&Kl[32 + ln][dk*16 + h*8];
      s1 = __builtin_amdgcn_mfma_f32_32x32x16_bf16(kf, qf[dk], s1, 0,0,0);
    }
    // p = 2^score; lr is a plain scalar (q lives on the lane)
    for (int r=0;r<16;r++){ s0[r] = __builtin_amdgcn_exp2f(s0[r]); lr += s0[r]; }
    for (int r=0;r<16;r++){ s1[r] = __builtin_amdgcn_exp2f(s1[r]); lr += s1[r]; }

    // PV: A-frag gather via lane^32 exchange, then 4 ct tiles of V
#define PV_STEP(SV, KS)                                                        \
    {                                                                          \
      short8 pf;                                                               \
      _Pragma("unroll")                                                        \
      for (int b2=0;b2<4;b2++){                                                \
        const int r0 = ((KS)&1)*8 + b2, r1 = r0 + 4;                           \
        float own = h ? (SV)[r1] : (SV)[r0];                                   \
        float snd = h ? (SV)[r0] : (SV)[r1];                                   \
        float oth = __shfl_xor(snd, 32, 64);                                   \
        float fl  = h ? oth : own;                                             \
        float fh  = h ? own : oth;                                             \
        pf[b2]   = (short)f2b_trunc(fl);                                       \
        pf[4+b2] = (short)f2b_trunc(fh);                                       \
      }                                                                        \
      _Pragma("unroll")                                                        \
      for (int ct=0;ct<4;ct++){                                                \
        short8 vf = *(const short8*)&Vl[ct*32 + ln][(KS)*16 + h*8];            \
        Oc[ct] = __builtin_amdgcn_mfma_f32_32x32x16_bf16(pf, vf, Oc[ct], 0,0,0);\
      }                                                                        \
    }
    PV_STEP(s0, 0) PV_STEP(s0, 1) PV_STEP(s1, 2) PV_STEP(s1, 3)
#undef PV_STEP
  }

  // epilogue
  lr += __shfl_xor(lr, 32, 64);
  float inv = 1.f / lr;
  __syncthreads();                 // everyone done with K/V LDS
  if (h == 0) invL[w][ln] = inv;
  __asm__ volatile("s_waitcnt lgkmcnt(0)" ::: "memory");
  float iv[16];
  for (int r=0;r<16;r++) iv[r] = invL[w][(r&3) + 8*(r>>2) + 4*h];

  unsigned short* stg = smem + w*(32*KSTR);     // 32x132 bf16 per wave
  for (int ct=0;ct<4;ct++)
    for (int r=0;r<16;r++){
      int row = (r&3) + 8*(r>>2) + 4*h;
      stg[row*KSTR + ct*32 + ln] = f2b(Oc[ct][r]*iv[r]);
    }
  __asm__ volatile("s_waitcnt lgkmcnt(0)" ::: "memory");
  if (q0w < HW){
    unsigned short* ob = Og + ((size_t)t*NB + b)*HW*CD + (size_t)q0w*CD;
    for (int i=0;i<16;i++){
      int row2 = i*2 + h;
      ushort4v v4 = *(const ushort4v*)&stg[row2*KSTR + ln*4];
      *(ushort4v*)&ob[(size_t)row2*CD + ln*4] = v4;
    }
  }
}

// ---------------------------------------------------------------------------
// out[b,c,hw] = s[b,c,hw] + 0.5*(O1[b,hw,c] + O2[b,hw,c])
// ---------------------------------------------------------------------------
__global__ __launch_bounds__(256) void combine_kernel(
    const float* __restrict__ s, const unsigned short* __restrict__ Og,
    float* __restrict__ out)
{
  __shared__ float T[32][129];
  const int b   = blockIdx.y;
  const int hw0 = blockIdx.x * 32;
  const int tid = threadIdx.x;
  const unsigned short* O1 = Og + ((size_t)b*HW + hw0)*CD;
  const unsigned short* O2 = O1 + (size_t)NB*HW*CD;
  for (int i=0;i<2;i++){
    int flat = (tid + i*256)*8;
    int row = flat >> 7, col = flat & 127;
    short8 a  = *(const short8*)(O1 + (size_t)row*CD + col);
    short8 c2 = *(const short8*)(O2 + (size_t)row*CD + col);
    for (int j=0;j<8;j++)
      T[row][col+j] = 0.5f*(b2f((unsigned short)a[j]) + b2f((unsigned short)c2[j]));
  }
  __syncthreads();
  const int c  = tid >> 1;
  const int h0 = (tid & 1)*16;
  const float* sr = s   + ((size_t)b*CD + c)*HW + hw0 + h0;
  float*     orow = out + ((size_t)b*CD + c)*HW + hw0 + h0;
  for (int j0=0;j0<16;j0+=4){
    floatx4 sv = *(const floatx4*)(sr + j0);
    floatx4 ov;
    for (int jj=0;jj<4;jj++) ov[jj] = sv[jj] + T[h0+j0+jj][c];
    *(floatx4*)(orow + j0) = ov;
  }
}

extern "C" void kernel_launch(void* const* d_in, const int* in_sizes, int n_in,
                              void* d_out, int out_size, void* d_ws, size_t ws_size,
                              hipStream_t stream)
{
  const float* s  = (const float*)d_in[0];
  const float* t1 = (const float*)d_in[1];
  const float* t2 = (const float*)d_in[2];
  const float* wq = (const float*)d_in[3];
  const float* bq = (const float*)d_in[4];
  const float* wk = (const float*)d_in[5];
  const float* bk = (const float*)d_in[6];
  const float* wv = (const float*)d_in[7];
  const float* bv = (const float*)d_in[8];
  float* out = (float*)d_out;

  unsigned short* qkv = (unsigned short*)d_ws;
  unsigned short* Og  = qkv + (size_t)5*NB*HW*CD;

  hipLaunchKernelGGL(proj_kernel,    dim3(49,5),   dim3(256), 0, stream,
                     s,t1,t2,wq,bq,wk,bk,wv,bv,qkv);
  hipLaunchKernelGGL(attn_kernel,    dim3(25,8,2), dim3(256), 0, stream, qkv, Og);
  hipLaunchKernelGGL(combine_kernel, dim3(98,8),   dim3(256), 0, stream, s, Og, out);
}